// Round 14
// baseline (63.392 us; speedup 1.0000x reference)
//
#include <hip/hip_runtime.h>
#include <hip/hip_bf16.h>

// KAN layer, round 14: DS diet within the 128-reg band + MFMA epilogue.
//  vs r12: (1) hoist w0v/b0v + xms (bit_cast era, no unions -> no scratch);
//  (2) W2 rows rho-permuted too => relu(a2) packs into a B-frag over k=n2,
//      epilogue dot wo.relu(a2) = 2 MFMA vs wo A-frag (rows 1-15 zero);
//      p lands in lanes 0-15 reg0 -> no shfl chain;
//  (3) b1/b2 as MFMA C-inits at rho-logical offsets (r13-validated).
// DS/wave ~106 -> ~64. Swapped GEMM D[n][m]=W[n][k]*H[m][k]; XOR swizzle.

#define D_EDGES 4096

typedef __attribute__((ext_vector_type(4))) float f32x4;
typedef __attribute__((ext_vector_type(8))) short bf16x8;

__device__ __forceinline__ unsigned pk2(float a, float b) {
    __hip_bfloat162 h = __float22bfloat162_rn(float2{a, b});
    return *reinterpret_cast<unsigned*>(&h);
}

__device__ __forceinline__ bf16x8 mk8(unsigned a, unsigned b, unsigned c, unsigned d) {
    uint4 u{a, b, c, d};
    return __builtin_bit_cast(bf16x8, u);
}

// logical row n -> physical storage row: (c g1 g0 e r1 r0) -> (c e g1 g0 r1 r0)
__device__ __forceinline__ int rho(int n) {
    return (n & 0x23) | ((n & 0x18) >> 1) | ((n & 0x04) << 2);
}

__global__ __launch_bounds__(256, 4) void kan_mfma(
    const float* __restrict__ x,     // (256, 64)
    const float* __restrict__ w0g,   // (D, 64)
    const float* __restrict__ b0g,   // (D, 64)
    const float* __restrict__ w1g,   // (D, 64, 64)
    const float* __restrict__ b1g,   // (D, 64)
    const float* __restrict__ w2g,   // (D, 64, 64)
    const float* __restrict__ b2g,   // (D, 64)
    const float* __restrict__ woutg, // (64, 4096)
    float* __restrict__ outbuf,      // partial (D,256) or y (256,64)
    int atomic_mode)
{
    const int d = blockIdx.x, o = d >> 6, ii = d & 63;
    const int t = threadIdx.x;
    const int lane = t & 63, wv = t >> 6;

    __shared__ __align__(16) unsigned char W1s[64 * 128];    // rho-permuted rows
    __shared__ __align__(16) unsigned char W2s[64 * 128];    // rho-permuted rows
    __shared__ __align__(16) float sx[256];
    __shared__ __align__(16) float sw0[64], sb0[64], sb1[64], sb2[64], swo[64];

    // ---- stage W1, W2 (both row-permuted) -> bf16, swizzled ----
    {
        const int orow = t >> 2, q = t & 3;          // logical row, quarter
        const int prow = rho(orow);                   // physical row
        const unsigned swz  = (unsigned)((prow & 7) << 4);
        const unsigned base = (unsigned)(prow * 128);
        const float* s1 = w1g + (size_t)d * 4096 + orow * 64 + q * 16;
        const float* s2 = w2g + (size_t)d * 4096 + orow * 64 + q * 16;

        float4 a0 = ((const float4*)s1)[0], a1 = ((const float4*)s1)[1];
        float4 a2 = ((const float4*)s1)[2], a3 = ((const float4*)s1)[3];
        uint4 u0 = { pk2(a0.x, a0.y), pk2(a0.z, a0.w), pk2(a1.x, a1.y), pk2(a1.z, a1.w) };
        uint4 u1 = { pk2(a2.x, a2.y), pk2(a2.z, a2.w), pk2(a3.x, a3.y), pk2(a3.z, a3.w) };
        *(uint4*)&W1s[base + ((unsigned)(q * 32)      ^ swz)] = u0;
        *(uint4*)&W1s[base + ((unsigned)(q * 32 + 16) ^ swz)] = u1;

        a0 = ((const float4*)s2)[0]; a1 = ((const float4*)s2)[1];
        a2 = ((const float4*)s2)[2]; a3 = ((const float4*)s2)[3];
        uint4 v0 = { pk2(a0.x, a0.y), pk2(a0.z, a0.w), pk2(a1.x, a1.y), pk2(a1.z, a1.w) };
        uint4 v1 = { pk2(a2.x, a2.y), pk2(a2.z, a2.w), pk2(a3.x, a3.y), pk2(a3.z, a3.w) };
        *(uint4*)&W2s[base + ((unsigned)(q * 32)      ^ swz)] = v0;
        *(uint4*)&W2s[base + ((unsigned)(q * 32 + 16) ^ swz)] = v1;
    }
    sx[t] = x[t * 64 + ii];
    if (t < 64) {
        sw0[t] = w0g[(size_t)d * 64 + t];
        sb0[t] = b0g[(size_t)d * 64 + t];
        sb1[t] = b1g[(size_t)d * 64 + t];
        sb2[t] = b2g[(size_t)d * 64 + t];
        swo[t] = woutg[(size_t)o * 4096 + ii * 64 + t];
    }
    __syncthreads();   // the only block-wide barrier

    const int arow = lane & 15;
    const int kb   = (lane >> 4) * 16;     // byte offset of this lane's 8 k-elems
    const int g8   = (lane >> 4) * 8;      // element offset (8*g)
    const unsigned lswz = (unsigned)((lane & 7) << 4);
    const f32x4 zero4 = { 0.f, 0.f, 0.f, 0.f };

    // ---- hoisted: A-fragments for both layers ----
    bf16x8 wf1[4][2], wf2[4][2];
#pragma unroll
    for (int nt = 0; nt < 4; ++nt)
#pragma unroll
        for (int ks = 0; ks < 2; ++ks) {
            wf1[nt][ks] = *(const bf16x8*)&W1s[(nt * 16 + arow) * 128 +
                            ((unsigned)(ks * 64 + kb) ^ lswz)];
            wf2[nt][ks] = *(const bf16x8*)&W2s[(nt * 16 + arow) * 128 +
                            ((unsigned)(ks * 64 + kb) ^ lswz)];
        }

    // ---- hoisted: w0/b0 slices, x values, wo A-fragment ----
    float4 w0v[2][2], b0v[2][2];
#pragma unroll
    for (int ks = 0; ks < 2; ++ks) {
        const int k0 = ks * 32 + g8;
        w0v[ks][0] = *(const float4*)&sw0[k0];
        w0v[ks][1] = *(const float4*)&sw0[k0 + 4];
        b0v[ks][0] = *(const float4*)&sb0[k0];
        b0v[ks][1] = *(const float4*)&sb0[k0 + 4];
    }
    float xms[4];
#pragma unroll
    for (int mti = 0; mti < 4; ++mti)
        xms[mti] = sx[wv * 64 + mti * 16 + arow];

    bf16x8 woA[2];   // A-frag: row 0 = wout slice, rows 1-15 = 0
#pragma unroll
    for (int ks = 0; ks < 2; ++ks) {
        const int k0 = ks * 32 + g8;
        float4 wa = *(const float4*)&swo[k0];
        float4 wb = *(const float4*)&swo[k0 + 4];
        unsigned u0 = pk2(wa.x, wa.y), u1 = pk2(wa.z, wa.w);
        unsigned u2 = pk2(wb.x, wb.y), u3 = pk2(wb.z, wb.w);
        const bool keep = (arow == 0);
        woA[ks] = mk8(keep ? u0 : 0u, keep ? u1 : 0u,
                      keep ? u2 : 0u, keep ? u3 : 0u);
    }

#pragma unroll
    for (int mti = 0; mti < 4; ++mti) {
        const float xm = xms[mti];

        // ---- layer 1: C-init = b1 at rho-logical offsets ----
        f32x4 a1[4];
#pragma unroll
        for (int nt = 0; nt < 4; ++nt) {
            const int bb_ = ((nt >> 1) << 5) + ((nt & 1) << 2) + g8;
            a1[nt] = *(const f32x4*)&sb1[bb_];
        }
#pragma unroll
        for (int ks = 0; ks < 2; ++ks) {
            float4 wa = w0v[ks][0], wb = w0v[ks][1];
            float4 ba = b0v[ks][0], bb = b0v[ks][1];
            float v0 = fmaxf(fmaf(xm, wa.x, ba.x), 0.f);
            float v1 = fmaxf(fmaf(xm, wa.y, ba.y), 0.f);
            float v2 = fmaxf(fmaf(xm, wa.z, ba.z), 0.f);
            float v3 = fmaxf(fmaf(xm, wa.w, ba.w), 0.f);
            float v4 = fmaxf(fmaf(xm, wb.x, bb.x), 0.f);
            float v5 = fmaxf(fmaf(xm, wb.y, bb.y), 0.f);
            float v6 = fmaxf(fmaf(xm, wb.z, bb.z), 0.f);
            float v7 = fmaxf(fmaf(xm, wb.w, bb.w), 0.f);
            bf16x8 bh = mk8(pk2(v0, v1), pk2(v2, v3), pk2(v4, v5), pk2(v6, v7));
#pragma unroll
            for (int nt = 0; nt < 4; ++nt)
                a1[nt] = __builtin_amdgcn_mfma_f32_16x16x32_bf16(
                    wf1[nt][ks], bh, a1[nt], 0, 0, 0);
        }

        // ---- H1 = relu(a1): pack into layer-2 B-frags (bias already in) ----
        bf16x8 f0 = mk8(
            pk2(fmaxf(a1[0][0], 0.f), fmaxf(a1[0][1], 0.f)),
            pk2(fmaxf(a1[0][2], 0.f), fmaxf(a1[0][3], 0.f)),
            pk2(fmaxf(a1[1][0], 0.f), fmaxf(a1[1][1], 0.f)),
            pk2(fmaxf(a1[1][2], 0.f), fmaxf(a1[1][3], 0.f)));
        bf16x8 f1 = mk8(
            pk2(fmaxf(a1[2][0], 0.f), fmaxf(a1[2][1], 0.f)),
            pk2(fmaxf(a1[2][2], 0.f), fmaxf(a1[2][3], 0.f)),
            pk2(fmaxf(a1[3][0], 0.f), fmaxf(a1[3][1], 0.f)),
            pk2(fmaxf(a1[3][2], 0.f), fmaxf(a1[3][3], 0.f)));

        // ---- layer 2: C-init = b2 at rho-logical offsets (W2 rho-permuted) ----
        f32x4 a2[4];
#pragma unroll
        for (int nt = 0; nt < 4; ++nt) {
            const int bb_ = ((nt >> 1) << 5) + ((nt & 1) << 2) + g8;
            a2[nt] = *(const f32x4*)&sb2[bb_];
        }
#pragma unroll
        for (int nt = 0; nt < 4; ++nt) {
            a2[nt] = __builtin_amdgcn_mfma_f32_16x16x32_bf16(
                wf2[nt][0], f0, a2[nt], 0, 0, 0);
            a2[nt] = __builtin_amdgcn_mfma_f32_16x16x32_bf16(
                wf2[nt][1], f1, a2[nt], 0, 0, 0);
        }

        // ---- epilogue: H2 = relu(a2) packs into B-frags over k=n2;
        //      p = wo . H2 via 2 MFMAs against woA (row 0 only) ----
        bf16x8 e0 = mk8(
            pk2(fmaxf(a2[0][0], 0.f), fmaxf(a2[0][1], 0.f)),
            pk2(fmaxf(a2[0][2], 0.f), fmaxf(a2[0][3], 0.f)),
            pk2(fmaxf(a2[1][0], 0.f), fmaxf(a2[1][1], 0.f)),
            pk2(fmaxf(a2[1][2], 0.f), fmaxf(a2[1][3], 0.f)));
        bf16x8 e1 = mk8(
            pk2(fmaxf(a2[2][0], 0.f), fmaxf(a2[2][1], 0.f)),
            pk2(fmaxf(a2[2][2], 0.f), fmaxf(a2[2][3], 0.f)),
            pk2(fmaxf(a2[3][0], 0.f), fmaxf(a2[3][1], 0.f)),
            pk2(fmaxf(a2[3][2], 0.f), fmaxf(a2[3][3], 0.f)));

        f32x4 p3 = zero4;
        p3 = __builtin_amdgcn_mfma_f32_16x16x32_bf16(woA[0], e0, p3, 0, 0, 0);
        p3 = __builtin_amdgcn_mfma_f32_16x16x32_bf16(woA[1], e1, p3, 0, 0, 0);

        // D3[0][m]: lanes 0-15 (g=0), reg 0. m = lane.
        const int b = wv * 64 + mti * 16 + arow;
        if (lane < 16) {
            if (atomic_mode) atomicAdd(&outbuf[b * 64 + o], p3[0]);
            else             outbuf[(size_t)d * 256 + b] = p3[0];
        }
    }
}

// Deterministic reduction over ii: y[b,o] = bout[o] + sum_ii partial[(o*64+ii)*256 + b]
// grid (64 o, 4 bq) x 64 threads -> 256 blocks.
__global__ __launch_bounds__(64) void kan_reduce(
    const float* __restrict__ partial,
    const float* __restrict__ bout,
    float* __restrict__ y)
{
    const int o  = blockIdx.x;                     // 64
    const int b  = blockIdx.y * 64 + threadIdx.x;  // 256
    float acc = bout[o];
    const float* p = partial + (size_t)o * (64 * 256) + b;
#pragma unroll
    for (int i = 0; i < 64; ++i)
        acc += p[i * 256];
    y[b * 64 + o] = acc;
}

__global__ __launch_bounds__(256) void kan_init_out(const float* __restrict__ bout,
                                                    float* __restrict__ y)
{
    const int idx = blockIdx.x * 256 + threadIdx.x;
    y[idx] = bout[idx & 63];
}

extern "C" void kernel_launch(void* const* d_in, const int* in_sizes, int n_in,
                              void* d_out, int out_size, void* d_ws, size_t ws_size,
                              hipStream_t stream) {
    const float* x    = (const float*)d_in[0];
    const float* w0   = (const float*)d_in[1];
    const float* b0   = (const float*)d_in[2];
    const float* w1   = (const float*)d_in[3];
    const float* b1   = (const float*)d_in[4];
    const float* w2   = (const float*)d_in[5];
    const float* b2   = (const float*)d_in[6];
    const float* wout = (const float*)d_in[7];
    const float* bout = (const float*)d_in[8];
    float* y = (float*)d_out;

    const size_t partial_bytes = (size_t)D_EDGES * 256 * sizeof(float); // 4 MB

    if (ws_size >= partial_bytes) {
        float* partial = (float*)d_ws;
        kan_mfma<<<D_EDGES, 256, 0, stream>>>(x, w0, b0, w1, b1, w2, b2, wout, partial, 0);
        kan_reduce<<<dim3(64, 4), 64, 0, stream>>>(partial, bout, y);
    } else {
        kan_init_out<<<64, 256, 0, stream>>>(bout, y);
        kan_mfma<<<D_EDGES, 256, 0, stream>>>(x, w0, b0, w1, b1, w2, b2, wout, y, 1);
    }
}

// Round 15
// 42.686 us; speedup vs baseline: 1.4851x; 1.4851x over previous
//
#include <hip/hip_runtime.h>
#include <hip/hip_bf16.h>

// KAN layer, round 15: r14's validated wins WITHOUT its spilling hoists.
//  = r12 base (w0/b0/x read from LDS per mti -- the clean 64-VGPR config)
//  + W2 rows rho-permuted (r14-validated)
//  + b1/b2 as MFMA C-inits at rho-logical offsets (r14-validated)
//  + MFMA epilogue: p = wo . relu(a2) via 2 MFMAs vs woA A-frag (rows 1-15
//    zero), p lands in lanes 0-15 reg0 -> no shfl chain, no per-mti swo reads.
// Register roster ~55 arch (wf1 16 + wf2 16 + woA 8 + temps) = r12-class.
// Swapped GEMM D[n][m]=W[n][k]*H[m][k]; XOR swizzle byte ^= (row&7)<<4.

#define D_EDGES 4096

typedef __attribute__((ext_vector_type(4))) float f32x4;
typedef __attribute__((ext_vector_type(8))) short bf16x8;

__device__ __forceinline__ unsigned pk2(float a, float b) {
    __hip_bfloat162 h = __float22bfloat162_rn(float2{a, b});
    return *reinterpret_cast<unsigned*>(&h);
}

__device__ __forceinline__ bf16x8 mk8(unsigned a, unsigned b, unsigned c, unsigned d) {
    uint4 u{a, b, c, d};
    return __builtin_bit_cast(bf16x8, u);
}

// logical row n -> physical storage row: (c g1 g0 e r1 r0) -> (c e g1 g0 r1 r0)
__device__ __forceinline__ int rho(int n) {
    return (n & 0x23) | ((n & 0x18) >> 1) | ((n & 0x04) << 2);
}

__global__ __launch_bounds__(256, 4) void kan_mfma(
    const float* __restrict__ x,     // (256, 64)
    const float* __restrict__ w0g,   // (D, 64)
    const float* __restrict__ b0g,   // (D, 64)
    const float* __restrict__ w1g,   // (D, 64, 64)
    const float* __restrict__ b1g,   // (D, 64)
    const float* __restrict__ w2g,   // (D, 64, 64)
    const float* __restrict__ b2g,   // (D, 64)
    const float* __restrict__ woutg, // (64, 4096)
    float* __restrict__ outbuf,      // partial (D,256) or y (256,64)
    int atomic_mode)
{
    const int d = blockIdx.x, o = d >> 6, ii = d & 63;
    const int t = threadIdx.x;
    const int lane = t & 63, wv = t >> 6;

    __shared__ __align__(16) unsigned char W1s[64 * 128];    // rho-permuted rows
    __shared__ __align__(16) unsigned char W2s[64 * 128];    // rho-permuted rows
    __shared__ __align__(16) float sx[256];
    __shared__ __align__(16) float sw0[64], sb0[64], sb1[64], sb2[64], swo[64];

    // ---- stage W1, W2 (both row-permuted) -> bf16, swizzled ----
    {
        const int orow = t >> 2, q = t & 3;          // logical row, quarter
        const int prow = rho(orow);                   // physical row
        const unsigned swz  = (unsigned)((prow & 7) << 4);
        const unsigned base = (unsigned)(prow * 128);
        const float* s1 = w1g + (size_t)d * 4096 + orow * 64 + q * 16;
        const float* s2 = w2g + (size_t)d * 4096 + orow * 64 + q * 16;

        float4 a0 = ((const float4*)s1)[0], a1 = ((const float4*)s1)[1];
        float4 a2 = ((const float4*)s1)[2], a3 = ((const float4*)s1)[3];
        uint4 u0 = { pk2(a0.x, a0.y), pk2(a0.z, a0.w), pk2(a1.x, a1.y), pk2(a1.z, a1.w) };
        uint4 u1 = { pk2(a2.x, a2.y), pk2(a2.z, a2.w), pk2(a3.x, a3.y), pk2(a3.z, a3.w) };
        *(uint4*)&W1s[base + ((unsigned)(q * 32)      ^ swz)] = u0;
        *(uint4*)&W1s[base + ((unsigned)(q * 32 + 16) ^ swz)] = u1;

        a0 = ((const float4*)s2)[0]; a1 = ((const float4*)s2)[1];
        a2 = ((const float4*)s2)[2]; a3 = ((const float4*)s2)[3];
        uint4 v0 = { pk2(a0.x, a0.y), pk2(a0.z, a0.w), pk2(a1.x, a1.y), pk2(a1.z, a1.w) };
        uint4 v1 = { pk2(a2.x, a2.y), pk2(a2.z, a2.w), pk2(a3.x, a3.y), pk2(a3.z, a3.w) };
        *(uint4*)&W2s[base + ((unsigned)(q * 32)      ^ swz)] = v0;
        *(uint4*)&W2s[base + ((unsigned)(q * 32 + 16) ^ swz)] = v1;
    }
    sx[t] = x[t * 64 + ii];
    if (t < 64) {
        sw0[t] = w0g[(size_t)d * 64 + t];
        sb0[t] = b0g[(size_t)d * 64 + t];
        sb1[t] = b1g[(size_t)d * 64 + t];
        sb2[t] = b2g[(size_t)d * 64 + t];
        swo[t] = woutg[(size_t)o * 4096 + ii * 64 + t];
    }
    __syncthreads();   // the only block-wide barrier

    const int arow = lane & 15;
    const int kb   = (lane >> 4) * 16;     // byte offset of this lane's 8 k-elems
    const int g8   = (lane >> 4) * 8;      // element offset (8*g)
    const unsigned lswz = (unsigned)((lane & 7) << 4);
    const f32x4 zero4 = { 0.f, 0.f, 0.f, 0.f };

    // ---- hoisted: A-fragments for both layers ----
    bf16x8 wf1[4][2], wf2[4][2];
#pragma unroll
    for (int nt = 0; nt < 4; ++nt)
#pragma unroll
        for (int ks = 0; ks < 2; ++ks) {
            wf1[nt][ks] = *(const bf16x8*)&W1s[(nt * 16 + arow) * 128 +
                            ((unsigned)(ks * 64 + kb) ^ lswz)];
            wf2[nt][ks] = *(const bf16x8*)&W2s[(nt * 16 + arow) * 128 +
                            ((unsigned)(ks * 64 + kb) ^ lswz)];
        }

    // ---- hoisted: wo A-fragment (row 0 = wout slice, rows 1-15 = 0) ----
    bf16x8 woA[2];
#pragma unroll
    for (int ks = 0; ks < 2; ++ks) {
        const int k0 = ks * 32 + g8;
        float4 wa = *(const float4*)&swo[k0];
        float4 wb = *(const float4*)&swo[k0 + 4];
        unsigned u0 = pk2(wa.x, wa.y), u1 = pk2(wa.z, wa.w);
        unsigned u2 = pk2(wb.x, wb.y), u3 = pk2(wb.z, wb.w);
        const bool keep = (arow == 0);
        woA[ks] = mk8(keep ? u0 : 0u, keep ? u1 : 0u,
                      keep ? u2 : 0u, keep ? u3 : 0u);
    }

#pragma unroll
    for (int mti = 0; mti < 4; ++mti) {
        const float xm = sx[wv * 64 + mti * 16 + arow];

        // ---- layer 1: C-init = b1 at rho-logical offsets ----
        f32x4 a1[4];
#pragma unroll
        for (int nt = 0; nt < 4; ++nt) {
            const int bb_ = ((nt >> 1) << 5) + ((nt & 1) << 2) + g8;
            a1[nt] = *(const f32x4*)&sb1[bb_];
        }
        // B-frags from LDS w0/b0 (per-mti reads: clean-VGPR config)
#pragma unroll
        for (int ks = 0; ks < 2; ++ks) {
            const int k0 = ks * 32 + g8;
            float4 wa = *(const float4*)&sw0[k0];
            float4 wb = *(const float4*)&sw0[k0 + 4];
            float4 ba = *(const float4*)&sb0[k0];
            float4 bb = *(const float4*)&sb0[k0 + 4];
            float v0 = fmaxf(fmaf(xm, wa.x, ba.x), 0.f);
            float v1 = fmaxf(fmaf(xm, wa.y, ba.y), 0.f);
            float v2 = fmaxf(fmaf(xm, wa.z, ba.z), 0.f);
            float v3 = fmaxf(fmaf(xm, wa.w, ba.w), 0.f);
            float v4 = fmaxf(fmaf(xm, wb.x, bb.x), 0.f);
            float v5 = fmaxf(fmaf(xm, wb.y, bb.y), 0.f);
            float v6 = fmaxf(fmaf(xm, wb.z, bb.z), 0.f);
            float v7 = fmaxf(fmaf(xm, wb.w, bb.w), 0.f);
            bf16x8 bh = mk8(pk2(v0, v1), pk2(v2, v3), pk2(v4, v5), pk2(v6, v7));
#pragma unroll
            for (int nt = 0; nt < 4; ++nt)
                a1[nt] = __builtin_amdgcn_mfma_f32_16x16x32_bf16(
                    wf1[nt][ks], bh, a1[nt], 0, 0, 0);
        }

        // ---- H1 = relu(a1): pack into layer-2 B-frags (bias already in) ----
        bf16x8 f0 = mk8(
            pk2(fmaxf(a1[0][0], 0.f), fmaxf(a1[0][1], 0.f)),
            pk2(fmaxf(a1[0][2], 0.f), fmaxf(a1[0][3], 0.f)),
            pk2(fmaxf(a1[1][0], 0.f), fmaxf(a1[1][1], 0.f)),
            pk2(fmaxf(a1[1][2], 0.f), fmaxf(a1[1][3], 0.f)));
        bf16x8 f1 = mk8(
            pk2(fmaxf(a1[2][0], 0.f), fmaxf(a1[2][1], 0.f)),
            pk2(fmaxf(a1[2][2], 0.f), fmaxf(a1[2][3], 0.f)),
            pk2(fmaxf(a1[3][0], 0.f), fmaxf(a1[3][1], 0.f)),
            pk2(fmaxf(a1[3][2], 0.f), fmaxf(a1[3][3], 0.f)));

        // ---- layer 2: C-init = b2 at rho-logical offsets (W2 rho-permuted) ----
        f32x4 a2[4];
#pragma unroll
        for (int nt = 0; nt < 4; ++nt) {
            const int bb_ = ((nt >> 1) << 5) + ((nt & 1) << 2) + g8;
            a2[nt] = *(const f32x4*)&sb2[bb_];
        }
#pragma unroll
        for (int nt = 0; nt < 4; ++nt) {
            a2[nt] = __builtin_amdgcn_mfma_f32_16x16x32_bf16(
                wf2[nt][0], f0, a2[nt], 0, 0, 0);
            a2[nt] = __builtin_amdgcn_mfma_f32_16x16x32_bf16(
                wf2[nt][1], f1, a2[nt], 0, 0, 0);
        }

        // ---- epilogue: H2 = relu(a2) packs into B-frags over k=n2;
        //      p = wo . H2 via 2 MFMAs against woA (row 0 only) ----
        bf16x8 e0 = mk8(
            pk2(fmaxf(a2[0][0], 0.f), fmaxf(a2[0][1], 0.f)),
            pk2(fmaxf(a2[0][2], 0.f), fmaxf(a2[0][3], 0.f)),
            pk2(fmaxf(a2[1][0], 0.f), fmaxf(a2[1][1], 0.f)),
            pk2(fmaxf(a2[1][2], 0.f), fmaxf(a2[1][3], 0.f)));
        bf16x8 e1 = mk8(
            pk2(fmaxf(a2[2][0], 0.f), fmaxf(a2[2][1], 0.f)),
            pk2(fmaxf(a2[2][2], 0.f), fmaxf(a2[2][3], 0.f)),
            pk2(fmaxf(a2[3][0], 0.f), fmaxf(a2[3][1], 0.f)),
            pk2(fmaxf(a2[3][2], 0.f), fmaxf(a2[3][3], 0.f)));

        f32x4 p3 = zero4;
        p3 = __builtin_amdgcn_mfma_f32_16x16x32_bf16(woA[0], e0, p3, 0, 0, 0);
        p3 = __builtin_amdgcn_mfma_f32_16x16x32_bf16(woA[1], e1, p3, 0, 0, 0);

        // D3[0][m]: lanes 0-15 (g=0), reg 0. m = lane.
        const int b = wv * 64 + mti * 16 + arow;
        if (lane < 16) {
            if (atomic_mode) atomicAdd(&outbuf[b * 64 + o], p3[0]);
            else             outbuf[(size_t)d * 256 + b] = p3[0];
        }
    }
}

// Deterministic reduction over ii: y[b,o] = bout[o] + sum_ii partial[(o*64+ii)*256 + b]
// grid (64 o, 4 bq) x 64 threads -> 256 blocks.
__global__ __launch_bounds__(64) void kan_reduce(
    const float* __restrict__ partial,
    const float* __restrict__ bout,
    float* __restrict__ y)
{
    const int o  = blockIdx.x;                     // 64
    const int b  = blockIdx.y * 64 + threadIdx.x;  // 256
    float acc = bout[o];
    const float* p = partial + (size_t)o * (64 * 256) + b;
#pragma unroll
    for (int i = 0; i < 64; ++i)
        acc += p[i * 256];
    y[b * 64 + o] = acc;
}

__global__ __launch_bounds__(256) void kan_init_out(const float* __restrict__ bout,
                                                    float* __restrict__ y)
{
    const int idx = blockIdx.x * 256 + threadIdx.x;
    y[idx] = bout[idx & 63];
}

extern "C" void kernel_launch(void* const* d_in, const int* in_sizes, int n_in,
                              void* d_out, int out_size, void* d_ws, size_t ws_size,
                              hipStream_t stream) {
    const float* x    = (const float*)d_in[0];
    const float* w0   = (const float*)d_in[1];
    const float* b0   = (const float*)d_in[2];
    const float* w1   = (const float*)d_in[3];
    const float* b1   = (const float*)d_in[4];
    const float* w2   = (const float*)d_in[5];
    const float* b2   = (const float*)d_in[6];
    const float* wout = (const float*)d_in[7];
    const float* bout = (const float*)d_in[8];
    float* y = (float*)d_out;

    const size_t partial_bytes = (size_t)D_EDGES * 256 * sizeof(float); // 4 MB

    if (ws_size >= partial_bytes) {
        float* partial = (float*)d_ws;
        kan_mfma<<<D_EDGES, 256, 0, stream>>>(x, w0, b0, w1, b1, w2, b2, wout, partial, 0);
        kan_reduce<<<dim3(64, 4), 64, 0, stream>>>(partial, bout, y);
    } else {
        kan_init_out<<<64, 256, 0, stream>>>(bout, y);
        kan_mfma<<<D_EDGES, 256, 0, stream>>>(x, w0, b0, w1, b1, w2, b2, wout, y, 1);
    }
}